// Round 13
// baseline (828.020 us; speedup 1.0000x reference)
//
#include <hip/hip_runtime.h>
#include <hip/hip_bf16.h>
#include <stdint.h>

#define DEV __device__ __forceinline__

static constexpr int C_HID = 128;

DEV float4 f4_fma(float a, float4 w, float4 acc) {
  acc.x = fmaf(a, w.x, acc.x); acc.y = fmaf(a, w.y, acc.y);
  acc.z = fmaf(a, w.z, acc.z); acc.w = fmaf(a, w.w, acc.w);
  return acc;
}

// bf16 pack (RNE) / unpack helpers: uint2 holds 4 bf16 channels
DEV unsigned bfpack2(float a, float b) {
  unsigned ua = __float_as_uint(a), ub = __float_as_uint(b);
  ua += 0x7FFF + ((ua >> 16) & 1);
  ub += 0x7FFF + ((ub >> 16) & 1);
  return (ua >> 16) | (ub & 0xFFFF0000u);
}
DEV uint2 bfpack4(float4 v) { return make_uint2(bfpack2(v.x, v.y), bfpack2(v.z, v.w)); }
DEV float4 bfunpack4(uint2 u) {
  return make_float4(__uint_as_float(u.x << 16), __uint_as_float(u.x & 0xFFFF0000u),
                     __uint_as_float(u.y << 16), __uint_as_float(u.y & 0xFFFF0000u));
}

// ---------- score + keys (scores gate top-k set: fp32 upstream mandatory) ----------
__global__ void scorekeys_kernel(const float* __restrict__ x, const float* __restrict__ pw,
                                 float* __restrict__ score, unsigned long long* __restrict__ keys,
                                 int N) {
  int row = blockIdx.x * 4 + (threadIdx.x >> 6);
  int lane = threadIdx.x & 63;
  if (row >= N) return;
  float p0 = pw[lane], p1 = pw[lane + 64];
  float pn = p0 * p0 + p1 * p1;
  const float* xr = x + (size_t)row * C_HID;
  float s = xr[lane] * p0 + xr[lane + 64] * p1;
#pragma unroll
  for (int o = 32; o > 0; o >>= 1) {
    s += __shfl_xor(s, o, 64);
    pn += __shfl_xor(pn, o, 64);
  }
  if (lane == 0) {
    float sc = tanhf(s / sqrtf(pn));
    score[row] = sc;
    unsigned u = __float_as_uint(sc);
    u ^= (u >> 31) ? 0xFFFFFFFFu : 0x80000000u;
    keys[row] = (((unsigned long long)(~u)) << 16) | (unsigned)row;
  }
}

// ---------- radix pass-1 histogram: dense lanes (intra-wave merge) + 4 replicas ----------
__global__ void select_hist1_kernel(const unsigned long long* __restrict__ keys, int N,
                                    int* __restrict__ hist) {
  int i = blockIdx.x * 256 + threadIdx.x;
  if (i >= N) return;
  int bin = (int)((keys[i] >> 32) & 0xFFFF);
  atomicAdd(&hist[bin + ((blockIdx.x & 3) << 16)], 1);
}

// ---------- radix passes 2/3 histogram (prefix-filtered, low contention) ----------
__global__ void select_hist_kernel(const unsigned long long* __restrict__ keys, int N,
                                   const unsigned long long* __restrict__ prefix,
                                   int shift, unsigned long long M, int* __restrict__ hist) {
  int i = blockIdx.x * 256 + threadIdx.x;
  if (i >= N) return;
  unsigned long long P = *prefix;
  unsigned long long key = keys[i];
  if (((key ^ P) & M) == 0)
    atomicAdd(&hist[(int)((key >> shift) & 0xFFFF)], 1);
}

// find k-th digit; REPL=1 sums the 4 pass-1 replicas (merge folded in);
// pass1 (shift==32) seeds prefix/rem from param k.
template <int REPL>
__global__ void select_find_kernel(const int* __restrict__ hist,
                                   unsigned long long* __restrict__ prefix,
                                   int* __restrict__ rem, int shift, int* __restrict__ ctr,
                                   int k) {
  int t = threadIdx.x;            // 1024 threads
  int base = t * 64;
  int s = 0;
#pragma unroll
  for (int j = 0; j < 64; ++j) {
    int h = hist[base + j];
    if (REPL) h += hist[base + j + 65536] + hist[base + j + 2 * 65536] + hist[base + j + 3 * 65536];
    s += h;
  }
  int lane = t & 63, w = t >> 6;
  int v = s;
  for (int o = 1; o < 64; o <<= 1) { int u = __shfl_up(v, o, 64); if (lane >= o) v += u; }
  __shared__ int ws[16];
  if (lane == 63) ws[w] = v;
  __syncthreads();
  if (t < 16) {
    int u = ws[t];
    for (int o = 1; o < 16; o <<= 1) { int uu = __shfl_up(u, o, 64); if (t >= o) u += uu; }
    ws[t] = u;
  }
  __syncthreads();
  int incl = v + (w > 0 ? ws[w - 1] : 0);
  int excl = incl - s;
  int R = (shift == 32) ? k : *rem;
  if (excl < R && incl >= R) {
    int c = excl, b = base;
    for (int j = 0; j < 64; ++j) {
      int h = hist[base + j];
      if (REPL) h += hist[base + j + 65536] + hist[base + j + 2 * 65536] + hist[base + j + 3 * 65536];
      if (c + h >= R) { b = base + j; break; }
      c += h;
    }
    if (shift == 32) *prefix = ((unsigned long long)b) << shift;
    else             *prefix |= ((unsigned long long)b) << shift;
    *rem = R - c;
    if (shift == 0) *ctr = 0;
  }
}

__global__ void select_enum_kernel(const unsigned long long* __restrict__ keys, int N,
                                   const unsigned long long* __restrict__ Tptr,
                                   int* __restrict__ ctr, int* __restrict__ perm,
                                   int* __restrict__ nm) {
  int i = blockIdx.x * 256 + threadIdx.x;
  if (i >= N) return;
  unsigned long long T = *Tptr;
  if (keys[i] <= T) { int r = atomicAdd(ctr, 1); perm[r] = i; nm[i] = r; }
  else nm[i] = -1;
}

// ---------- pooled features: xnew[j] = xold[perm[j]] * score[perm[j]] ----------
// (kept standalone: fusing this gather into the k-tiled GEMM re-gathers 4x — round-12 lesson)
__global__ void pool_gather_kernel(const float* __restrict__ xold, const float* __restrict__ score,
                                   const int* __restrict__ perm, float* __restrict__ xnew, int k) {
  int j = blockIdx.x * 2 + (threadIdx.x >> 7);
  int f = threadIdx.x & 127;
  if (j >= k) return;
  int src = perm[j];
  xnew[(size_t)j * C_HID + f] = xold[(size_t)src * C_HID + f] * score[src];
}

// ---------- edge relabel chain ----------
DEV bool map_edge(int a, int b, const int* m0, const int* m1, int& r, int& c) {
  r = a; c = b;
  if (m0) { r = m0[r]; c = m0[c]; if ((r | c) < 0) return false; }
  if (m1) { r = m1[r]; c = m1[c]; if ((r | c) < 0) return false; }
  return true;
}

// level 0: plain count (identity mapping)
__global__ void edge_count_kernel(const int* __restrict__ ei, int E, int* __restrict__ cnt) {
  int e = blockIdx.x * 256 + threadIdx.x;
  if (e >= E) return;
  atomicAdd(&cnt[ei[e]], 1);
}

__global__ void edge_fill_kernel(const int* __restrict__ ei, int E,
                                 const int* __restrict__ rowptr, int* __restrict__ fc,
                                 int* __restrict__ colv) {
  int e = blockIdx.x * 256 + threadIdx.x;
  if (e >= E) return;
  int r = ei[e], c = ei[E + e];
  int pos = rowptr[r] + atomicAdd(&fc[r], 1);
  colv[pos] = c;
}

// mapped levels: count + compact surviving (r,c) pairs; block-aggregated pctr atomic.
#define CEPT 7
__global__ __launch_bounds__(1024) void edge_count_compact_kernel(
    const int* __restrict__ ei, int E, const int* m0, const int* m1,
    int* __restrict__ cnt, int2* __restrict__ pairs, int* __restrict__ pctr) {
  int tid = threadIdx.x;
  int gbase = blockIdx.x * (1024 * CEPT) + tid;
  int rs[CEPT], cs[CEPT];
  int myn = 0;
#pragma unroll
  for (int i = 0; i < CEPT; ++i) {
    int e = gbase + i * 1024;
    int r, c;
    bool keep = (e < E) && map_edge(ei[e], ei[E + e], m0, m1, r, c);
    rs[i] = keep ? r : -1;
    cs[i] = keep ? c : 0;
    if (keep) { atomicAdd(&cnt[r], 1); ++myn; }
  }
  int lane = tid & 63, w = tid >> 6;
  int v = myn;
  for (int o = 1; o < 64; o <<= 1) { int u = __shfl_up(v, o, 64); if (lane >= o) v += u; }
  __shared__ int ws[16];
  __shared__ int bbase;
  if (lane == 63) ws[w] = v;
  __syncthreads();
  if (tid < 16) {
    int u = ws[tid];
    for (int o = 1; o < 16; o <<= 1) { int uu = __shfl_up(u, o, 64); if (tid >= o) u += uu; }
    ws[tid] = u;
  }
  __syncthreads();
  int excl = v - myn + (w > 0 ? ws[w - 1] : 0);
  if (tid == 1023) bbase = atomicAdd(pctr, excl + myn);
  __syncthreads();
  int pos = bbase + excl;
#pragma unroll
  for (int i = 0; i < CEPT; ++i)
    if (rs[i] >= 0) pairs[pos++] = make_int2(rs[i], cs[i]);
}

__global__ void edge_fill_compact_kernel(const int2* __restrict__ pairs, const int* __restrict__ pctr,
                                         const int* __restrict__ rowptr, int* __restrict__ fc,
                                         int* __restrict__ colv) {
  int i = blockIdx.x * 256 + threadIdx.x;
  if (i >= *pctr) return;
  int2 pr = pairs[i];
  int pos = rowptr[pr.x] + atomicAdd(&fc[pr.x], 1);
  colv[pos] = pr.y;
}

// ---------- wide 3-phase scan (+ fused dinv, fc=0) ----------
__global__ void scan_partial_kernel(const int* __restrict__ cnt, int n, int* __restrict__ bsum) {
  int i = blockIdx.x * 256 + threadIdx.x;
  int v = (i < n) ? cnt[i] : 0;
#pragma unroll
  for (int o = 32; o > 0; o >>= 1) v += __shfl_down(v, o, 64);
  __shared__ int ws[4];
  if ((threadIdx.x & 63) == 0) ws[threadIdx.x >> 6] = v;
  __syncthreads();
  if (threadIdx.x == 0) bsum[blockIdx.x] = ws[0] + ws[1] + ws[2] + ws[3];
}

__global__ void scan_blocksums_kernel(int* __restrict__ bsum, int nb) {
  int t = threadIdx.x;
  int v = (t < nb) ? bsum[t] : 0;
  int lane = t & 63, w = t >> 6;
  for (int o = 1; o < 64; o <<= 1) { int u = __shfl_up(v, o, 64); if (lane >= o) v += u; }
  __shared__ int ws[16];
  if (lane == 63) ws[w] = v;
  __syncthreads();
  if (t < 16) {
    int u = ws[t];
    for (int o = 1; o < 16; o <<= 1) { int uu = __shfl_up(u, o, 64); if (t >= o) u += uu; }
    ws[t] = u;
  }
  __syncthreads();
  if (t < nb) bsum[t] = v + (w > 0 ? ws[w - 1] : 0);
}

__global__ void scan_scatter_kernel(const int* __restrict__ cnt, int n,
                                    const int* __restrict__ bsum,
                                    int* __restrict__ rowptr, float* __restrict__ dinv,
                                    int* __restrict__ fc) {
  int i = blockIdx.x * 256 + threadIdx.x;
  int v = (i < n) ? cnt[i] : 0;
  int lane = threadIdx.x & 63, w = threadIdx.x >> 6;
  int s = v;
  for (int o = 1; o < 64; o <<= 1) { int u = __shfl_up(s, o, 64); if (lane >= o) s += u; }
  __shared__ int ws[4];
  __shared__ int wo[4];
  if (lane == 63) ws[w] = s;
  __syncthreads();
  if (threadIdx.x == 0) { int c = 0; for (int j = 0; j < 4; ++j) { wo[j] = c; c += ws[j]; } }
  __syncthreads();
  int excl = s - v + wo[w] + (blockIdx.x > 0 ? bsum[blockIdx.x - 1] : 0);
  if (i < n) {
    rowptr[i] = excl;
    dinv[i] = rsqrtf((float)v + 1.0f);
    fc[i] = 0;
    if (i == n - 1) rowptr[n] = excl + v;
  }
}

// ---------- fp32 SpMM hop (pre-pool convs) ----------
template <int FIRST, int RELU>
__global__ void spmm_kernel(const int* __restrict__ rowptr, const int* __restrict__ colv,
                            const float* __restrict__ dinv,
                            const float* __restrict__ h_in, const float* __restrict__ x0,
                            float* __restrict__ out, int M, int C) {
  int lanes = C >> 2;
  int rpb = 256 / lanes;
  int r = blockIdx.x * rpb + (int)threadIdx.x / lanes;
  int lane = (int)threadIdx.x % lanes;
  if (r >= M) return;
  float d = dinv[r];
  const float4* hin4 = (const float4*)h_in;
  size_t base = (size_t)r * lanes + lane;
  float4 self = hin4[base];
  float sn = d * d;
  float4 v = make_float4(sn * self.x, sn * self.y, sn * self.z, sn * self.w);
  int e0 = rowptr[r], e1 = rowptr[r + 1];
  int e = e0;
  for (; e + 8 <= e1; e += 8) {
    int cc[8];
#pragma unroll
    for (int i = 0; i < 8; ++i) cc[i] = colv[e + i];
    float4 hh[8];
#pragma unroll
    for (int i = 0; i < 8; ++i) hh[i] = hin4[(size_t)cc[i] * lanes + lane];
    float ww[8];
#pragma unroll
    for (int i = 0; i < 8; ++i) ww[i] = d * dinv[cc[i]];
#pragma unroll
    for (int i = 0; i < 8; ++i) v = f4_fma(ww[i], hh[i], v);
  }
  for (; e < e1; ++e) {
    int c = colv[e];
    float w = d * dinv[c];
    float4 h = hin4[(size_t)c * lanes + lane];
    v = f4_fma(w, h, v);
  }
  if (FIRST) {
    ((float4*)out)[base] = v;
  } else {
    float4 a = ((const float4*)x0)[base];
    a.x += self.x + v.x; a.y += self.y + v.y; a.z += self.z + v.z; a.w += self.w + v.w;
    if (RELU) { a.x = fmaxf(a.x, 0.f); a.y = fmaxf(a.y, 0.f); a.z = fmaxf(a.z, 0.f); a.w = fmaxf(a.w, 0.f); }
    ((float4*)out)[base] = a;
  }
}

// ---------- bf16-gather SpMM hop (POST-POOL ONLY) ----------
template <int FIRST, int RELU>
__global__ void spmm_bf16_kernel(const int* __restrict__ rowptr, const int* __restrict__ colv,
                                 const float* __restrict__ dinv,
                                 const ushort* __restrict__ hb, const float* __restrict__ x0,
                                 void* __restrict__ outp, int M, int C) {
  int lanes = C >> 2;
  int rpb = 256 / lanes;
  int r = blockIdx.x * rpb + (int)threadIdx.x / lanes;
  int lane = (int)threadIdx.x % lanes;
  if (r >= M) return;
  float d = dinv[r];
  const uint2* hb2 = (const uint2*)hb;
  size_t base = (size_t)r * lanes + lane;
  float4 self = bfunpack4(hb2[base]);
  float sn = d * d;
  float4 v = make_float4(sn * self.x, sn * self.y, sn * self.z, sn * self.w);
  int e0 = rowptr[r], e1 = rowptr[r + 1];
  int e = e0;
  for (; e + 8 <= e1; e += 8) {
    int cc[8];
#pragma unroll
    for (int i = 0; i < 8; ++i) cc[i] = colv[e + i];
    uint2 hh[8];
#pragma unroll
    for (int i = 0; i < 8; ++i) hh[i] = hb2[(size_t)cc[i] * lanes + lane];
    float ww[8];
#pragma unroll
    for (int i = 0; i < 8; ++i) ww[i] = d * dinv[cc[i]];
#pragma unroll
    for (int i = 0; i < 8; ++i) v = f4_fma(ww[i], bfunpack4(hh[i]), v);
  }
  for (; e < e1; ++e) {
    int c = colv[e];
    float w = d * dinv[c];
    v = f4_fma(w, bfunpack4(hb2[(size_t)c * lanes + lane]), v);
  }
  if (FIRST) {
    ((uint2*)outp)[base] = bfpack4(v);
  } else {
    float4 a = ((const float4*)x0)[base];
    a.x += self.x + v.x; a.y += self.y + v.y; a.z += self.z + v.z; a.w += self.w + v.w;
    if (RELU) { a.x = fmaxf(a.x, 0.f); a.y = fmaxf(a.y, 0.f); a.z = fmaxf(a.z, 0.f); a.w = fmaxf(a.w, 0.f); }
    ((float4*)outp)[base] = a;
  }
}

// ---------- GEMM: C[M,NC] = A1eff @ W (+addv); optional bf16 mirror of output ----------
template <int NC, int KT, int SKIP, int ADDIN, int MIRROR>
__global__ __launch_bounds__(256) void gemm_kernel(const float* __restrict__ A1, int K1,
                                                   const float* __restrict__ W,
                                                   float* __restrict__ Cd, int M,
                                                   const float* __restrict__ up,
                                                   const int* __restrict__ nm,
                                                   const float* __restrict__ addv,
                                                   ushort* __restrict__ bh) {
  constexpr int KTILE = 32;
  constexpr int AP = KTILE + 4;
  constexpr int CG = NC / 4;
  constexpr int RG = 256 / CG;
  constexpr int RPT = 64 / RG;
  __shared__ float Wl[KTILE * NC];
  __shared__ float Al[64 * AP];
  int tid = threadIdx.x;
  int r0 = blockIdx.x * 64;
  int cg = tid % CG, rg = tid / CG;
  float4 acc[RPT];
#pragma unroll
  for (int m = 0; m < RPT; ++m) acc[m] = make_float4(0.f, 0.f, 0.f, 0.f);

  for (int k0 = 0; k0 < KT; k0 += KTILE) {
    const float4* Wg = (const float4*)(W + (size_t)k0 * NC);
    for (int idx = tid; idx < KTILE * NC / 4; idx += 256)
      ((float4*)Wl)[idx] = Wg[idx];
#pragma unroll
    for (int s = 0; s < (64 * KTILE / 4) / 256; ++s) {
      int f4i = tid + s * 256;
      int row = f4i >> 3;
      int kk = (f4i & 7) << 2;
      int gr = r0 + row, gk = k0 + kk;
      float4 v = make_float4(0.f, 0.f, 0.f, 0.f);
      if (gr < M) {
        v = *(const float4*)(A1 + (size_t)gr * K1 + gk);
        if (SKIP) {
          int j = nm[gr];
          if (j >= 0) {
            float4 u = *(const float4*)(up + (size_t)j * K1 + gk);
            v.x += u.x; v.y += u.y; v.z += u.z; v.w += u.w;
          }
        }
      }
      *(float4*)&Al[row * AP + kk] = v;
    }
    __syncthreads();
#pragma unroll
    for (int kk0 = 0; kk0 < KTILE; kk0 += 4) {
      float4 a4[RPT];
#pragma unroll
      for (int m = 0; m < RPT; ++m)
        a4[m] = *(const float4*)&Al[(rg * RPT + m) * AP + kk0];
#pragma unroll
      for (int j = 0; j < 4; ++j) {
        float4 w = *(const float4*)&Wl[(kk0 + j) * NC + cg * 4];
#pragma unroll
        for (int m = 0; m < RPT; ++m) {
          float a = (j == 0) ? a4[m].x : (j == 1) ? a4[m].y : (j == 2) ? a4[m].z : a4[m].w;
          acc[m] = f4_fma(a, w, acc[m]);
        }
      }
    }
    __syncthreads();
  }
#pragma unroll
  for (int m = 0; m < RPT; ++m) {
    int gr = r0 + rg * RPT + m;
    if (gr < M) {
      float4 o = acc[m];
      if (ADDIN) {
        float4 u = *(const float4*)(addv + (size_t)gr * NC + cg * 4);
        o.x += u.x; o.y += u.y; o.z += u.z; o.w += u.w;
      }
      *(float4*)(Cd + (size_t)gr * NC + cg * 4) = o;
      if (MIRROR) ((uint2*)bh)[(size_t)gr * CG + cg] = bfpack4(o);
    }
  }
}

extern "C" void kernel_launch(void* const* d_in, const int* in_sizes, int n_in,
                              void* d_out, int out_size, void* d_ws, size_t ws_size,
                              hipStream_t stream) {
  const float* x   = (const float*)d_in[0];
  const int*   ei  = (const int*)d_in[1];
  const float* Wd0 = (const float*)d_in[2];
  const float* Wd1 = (const float*)d_in[3];
  const float* Wd2 = (const float*)d_in[4];
  const float* pw0 = (const float*)d_in[5];
  const float* pw1 = (const float*)d_in[6];
  const float* Wu0 = (const float*)d_in[7];
  const float* Wu1 = (const float*)d_in[8];
  const float* Wu2 = (const float*)d_in[9];
  float* out = (float*)d_out;

  const int C = C_HID;
  int N0 = in_sizes[0] / C;       // 50000 (idx fits 16 bits -> 48-bit select keys)
  int E  = in_sizes[1] / 2;       // 800000
  int k1 = (N0 + 1) / 2;
  int k2 = (k1 + 1) / 2;

  char* p = (char*)d_ws;
  auto alloc = [&](size_t bytes) { char* q = p; p += (bytes + 255) & ~(size_t)255; return q; };
  float* org   = (float*)alloc((size_t)N0 * C * 4);
  float* b0    = (float*)alloc((size_t)N0 * C * 4);
  float* b1    = (float*)alloc((size_t)N0 * C * 4);
  float* b2    = (float*)alloc((size_t)N0 * C * 4);
  float* x1res = (float*)alloc((size_t)k1 * C * 4);
  ushort* bh   = (ushort*)alloc((size_t)N0 * C * 2);
  ushort* h1h  = (ushort*)alloc((size_t)N0 * C * 2);
  float* score = (float*)alloc((size_t)N0 * 4);
  unsigned long long* keys = (unsigned long long*)alloc((size_t)N0 * 8);
  int* perm0 = (int*)alloc((size_t)k1 * 4);
  int* perm1 = (int*)alloc((size_t)k2 * 4);
  int* map0  = (int*)alloc((size_t)N0 * 4);
  int* map1  = (int*)alloc((size_t)k1 * 4);
  int* cnt   = (int*)alloc((size_t)N0 * 4);
  int* fc    = (int*)alloc((size_t)N0 * 4);
  int* rp0   = (int*)alloc((size_t)(N0 + 1) * 4);
  int* rp1   = (int*)alloc((size_t)(k1 + 1) * 4);
  int* rp2   = (int*)alloc((size_t)(k2 + 1) * 4);
  float* dinv0 = (float*)alloc((size_t)N0 * 4);
  float* dinv1 = (float*)alloc((size_t)k1 * 4);
  float* dinv2 = (float*)alloc((size_t)k2 * 4);
  int* col0 = (int*)alloc((size_t)E * 4);
  int* col1 = (int*)alloc((size_t)E * 4);
  int* col2 = (int*)alloc((size_t)E * 4);
  int2* pairs = (int2*)alloc((size_t)E * 8);
  // per pool: 4 pass-1 replicas + pass2 + pass3 = 6 slices of 65536
  int* hist12 = (int*)alloc((size_t)12 * 65536 * 4);
  int* bsum = (int*)alloc(1024 * 4);
  float* Wcat1 = (float*)alloc((size_t)128 * 64 * 4);
  unsigned long long* selT = (unsigned long long*)alloc(64);
  int* selRem = (int*)alloc(64);
  int* selCtr = (int*)alloc(64);
  int* pctr = (int*)alloc(64);

  dim3 b256(256);
  int egrid = (E + 255) / 256;
  int cgrid = (E + 1024 * CEPT - 1) / (1024 * CEPT);
  int g0_128 = (N0 + 7) / 8;
  int g1_128 = (k1 + 7) / 8;
  int g2_128 = (k2 + 7) / 8;
  int g0_64  = (N0 + 15) / 16;

  auto scan_csr = [&](int n, int* rowptr, float* dinv) {
    int g = (n + 255) / 256;
    scan_partial_kernel<<<g, b256, 0, stream>>>(cnt, n, bsum);
    scan_blocksums_kernel<<<1, 1024, 0, stream>>>(bsum, g);
    scan_scatter_kernel<<<g, b256, 0, stream>>>(cnt, n, bsum, rowptr, dinv, fc);
  };

  auto topk_select = [&](int N, int k, int* perm, int* nm, int* histb) {
    int g = (N + 255) / 256;
    select_hist1_kernel<<<g, b256, 0, stream>>>(keys, N, histb);
    select_find_kernel<1><<<1, 1024, 0, stream>>>(histb, selT, selRem, 32, selCtr, k);
    select_hist_kernel<<<g, b256, 0, stream>>>(keys, N, selT, 16, ~0ull << 32, histb + 4 * 65536);
    select_find_kernel<0><<<1, 1024, 0, stream>>>(histb + 4 * 65536, selT, selRem, 16, selCtr, k);
    select_hist_kernel<<<g, b256, 0, stream>>>(keys, N, selT, 0, ~0ull << 16, histb + 5 * 65536);
    select_find_kernel<0><<<1, 1024, 0, stream>>>(histb + 5 * 65536, selT, selRem, 0, selCtr, k);
    select_enum_kernel<<<g, b256, 0, stream>>>(keys, N, selT, selCtr, perm, nm);
  };

  // zero all radix histograms once per call
  hipMemsetAsync(hist12, 0, (size_t)12 * 65536 * 4, stream);

  // ======== Wcat1 prep: Wcat1 = Wu1 @ Wu2[0:128]  [128x64]
  gemm_kernel<64, 128, 0, 0, 0><<<2, b256, 0, stream>>>(Wu1, 128, Wu2, Wcat1, 128, nullptr, nullptr, nullptr, nullptr);

  // ======== CSR level 0 ========
  hipMemsetAsync(cnt, 0, (size_t)N0 * 4, stream);
  edge_count_kernel<<<egrid, b256, 0, stream>>>(ei, E, cnt);
  scan_csr(N0, rp0, dinv0);
  edge_fill_kernel<<<egrid, b256, 0, stream>>>(ei, E, rp0, fc, col0);

  // ======== conv0 (PRE-POOL -> fp32): org = relu(x' + h1 + h2), x' = x @ Wd0 ========
  gemm_kernel<128, 128, 0, 0, 0><<<(N0 + 63) / 64, b256, 0, stream>>>(x, 128, Wd0, b0, N0, nullptr, nullptr, nullptr, nullptr);
  spmm_kernel<1, 0><<<g0_128, b256, 0, stream>>>(rp0, col0, dinv0, b0, nullptr, b1, N0, 128);
  spmm_kernel<0, 1><<<g0_128, b256, 0, stream>>>(rp0, col0, dinv0, b1, b0, org, N0, 128);

  // ======== pool0 ========
  scorekeys_kernel<<<(N0 + 3) / 4, b256, 0, stream>>>(org, pw0, score, keys, N0);
  topk_select(N0, k1, perm0, map0, hist12);
  pool_gather_kernel<<<(k1 + 1) / 2, b256, 0, stream>>>(org, score, perm0, b0, k1);

  // ======== CSR level 1 ========
  hipMemsetAsync(cnt, 0, (size_t)k1 * 4, stream);
  hipMemsetAsync(pctr, 0, 4, stream);
  edge_count_compact_kernel<<<cgrid, 1024, 0, stream>>>(ei, E, map0, nullptr, cnt, pairs, pctr);
  scan_csr(k1, rp1, dinv1);
  edge_fill_compact_kernel<<<egrid, b256, 0, stream>>>(pairs, pctr, rp1, fc, col1);

  // ======== conv1 (PRE-POOL -> fp32): x1res = relu(prop(b0 @ Wd1)) ========
  gemm_kernel<128, 128, 0, 0, 0><<<(k1 + 63) / 64, b256, 0, stream>>>(b0, 128, Wd1, b1, k1, nullptr, nullptr, nullptr, nullptr);
  spmm_kernel<1, 0><<<g1_128, b256, 0, stream>>>(rp1, col1, dinv1, b1, nullptr, b2, k1, 128);
  spmm_kernel<0, 1><<<g1_128, b256, 0, stream>>>(rp1, col1, dinv1, b2, b1, x1res, k1, 128);

  // ======== pool1 ========
  scorekeys_kernel<<<(k1 + 3) / 4, b256, 0, stream>>>(x1res, pw1, score, keys, k1);
  topk_select(k1, k2, perm1, map1, hist12 + 6 * 65536);
  pool_gather_kernel<<<(k2 + 1) / 2, b256, 0, stream>>>(x1res, score, perm1, b0, k2);

  // ======== CSR level 2 ========
  hipMemsetAsync(cnt, 0, (size_t)k2 * 4, stream);
  hipMemsetAsync(pctr, 0, 4, stream);
  edge_count_compact_kernel<<<cgrid, 1024, 0, stream>>>(ei, E, map0, map1, cnt, pairs, pctr);
  scan_csr(k2, rp2, dinv2);
  edge_fill_compact_kernel<<<egrid, b256, 0, stream>>>(pairs, pctr, rp2, fc, col2);

  // ======== conv2 (post-pool -> bf16 gathers): b0 = relu(prop(b0 @ Wd2)) ========
  gemm_kernel<128, 128, 0, 0, 1><<<(k2 + 63) / 64, b256, 0, stream>>>(b0, 128, Wd2, b1, k2, nullptr, nullptr, nullptr, bh);
  spmm_bf16_kernel<1, 0><<<g2_128, b256, 0, stream>>>(rp2, col2, dinv2, bh, nullptr, h1h, k2, 128);
  spmm_bf16_kernel<0, 1><<<g2_128, b256, 0, stream>>>(rp2, col2, dinv2, h1h, b1, b0, k2, 128);

  // ======== up0 (post-pool -> bf16): b0 = relu(prop((x1res + up(b0)) @ Wu0)) ========
  gemm_kernel<128, 128, 1, 0, 1><<<(k1 + 63) / 64, b256, 0, stream>>>(x1res, 128, Wu0, b1, k1, b0, map1, nullptr, bh);
  spmm_bf16_kernel<1, 0><<<g1_128, b256, 0, stream>>>(rp1, col1, dinv1, bh, nullptr, h1h, k1, 128);
  spmm_bf16_kernel<0, 1><<<g1_128, b256, 0, stream>>>(rp1, col1, dinv1, h1h, b1, b0, k1, 128);

  // ======== up1+final fusion (post-pool -> bf16 gathers, fp32 accumulate):
  //   out = P( P((org+up)@Wcat1) + org @ Wu2b ),  Wcat1 = Wu1@Wu2a
  gemm_kernel<64, 128, 1, 0, 1><<<(N0 + 63) / 64, b256, 0, stream>>>(org, 128, Wcat1, b2, N0, b0, map0, nullptr, bh);
  spmm_bf16_kernel<1, 0><<<g0_64, b256, 0, stream>>>(rp0, col0, dinv0, bh, nullptr, h1h, N0, 64);
  spmm_bf16_kernel<0, 0><<<g0_64, b256, 0, stream>>>(rp0, col0, dinv0, h1h, b2, b2, N0, 64);
  gemm_kernel<64, 128, 0, 1, 1><<<(N0 + 63) / 64, b256, 0, stream>>>(org, 128, Wu2 + (size_t)128 * 64, b0, N0, nullptr, nullptr, b2, bh);
  spmm_bf16_kernel<1, 0><<<g0_64, b256, 0, stream>>>(rp0, col0, dinv0, bh, nullptr, h1h, N0, 64);
  spmm_bf16_kernel<0, 0><<<g0_64, b256, 0, stream>>>(rp0, col0, dinv0, h1h, b0, out, N0, 64);
}

// Round 14
// 766.117 us; speedup vs baseline: 1.0808x; 1.0808x over previous
//
#include <hip/hip_runtime.h>
#include <hip/hip_bf16.h>
#include <stdint.h>

#define DEV __device__ __forceinline__

static constexpr int C_HID = 128;

DEV float4 f4_fma(float a, float4 w, float4 acc) {
  acc.x = fmaf(a, w.x, acc.x); acc.y = fmaf(a, w.y, acc.y);
  acc.z = fmaf(a, w.z, acc.z); acc.w = fmaf(a, w.w, acc.w);
  return acc;
}

// bf16 pack (RNE) / unpack helpers: uint2 holds 4 bf16 channels
DEV unsigned bfpack2(float a, float b) {
  unsigned ua = __float_as_uint(a), ub = __float_as_uint(b);
  ua += 0x7FFF + ((ua >> 16) & 1);
  ub += 0x7FFF + ((ub >> 16) & 1);
  return (ua >> 16) | (ub & 0xFFFF0000u);
}
DEV uint2 bfpack4(float4 v) { return make_uint2(bfpack2(v.x, v.y), bfpack2(v.z, v.w)); }
DEV float4 bfunpack4(uint2 u) {
  return make_float4(__uint_as_float(u.x << 16), __uint_as_float(u.x & 0xFFFF0000u),
                     __uint_as_float(u.y << 16), __uint_as_float(u.y & 0xFFFF0000u));
}

// ---------- score + keys (scores gate top-k set: fp32 upstream mandatory) ----------
__global__ void scorekeys_kernel(const float* __restrict__ x, const float* __restrict__ pw,
                                 float* __restrict__ score, unsigned long long* __restrict__ keys,
                                 int N) {
  int row = blockIdx.x * 4 + (threadIdx.x >> 6);
  int lane = threadIdx.x & 63;
  if (row >= N) return;
  float p0 = pw[lane], p1 = pw[lane + 64];
  float pn = p0 * p0 + p1 * p1;
  const float* xr = x + (size_t)row * C_HID;
  float s = xr[lane] * p0 + xr[lane + 64] * p1;
#pragma unroll
  for (int o = 32; o > 0; o >>= 1) {
    s += __shfl_xor(s, o, 64);
    pn += __shfl_xor(pn, o, 64);
  }
  if (lane == 0) {
    float sc = tanhf(s / sqrtf(pn));
    score[row] = sc;
    unsigned u = __float_as_uint(sc);
    u ^= (u >> 31) ? 0xFFFFFFFFu : 0x80000000u;
    keys[row] = (((unsigned long long)(~u)) << 16) | (unsigned)row;
  }
}

// ---------- radix pass-1 histogram: dense lanes (intra-wave merge) + 4 replicas ----------
__global__ void select_hist1_kernel(const unsigned long long* __restrict__ keys, int N,
                                    int* __restrict__ hist) {
  int i = blockIdx.x * 256 + threadIdx.x;
  if (i >= N) return;
  int bin = (int)((keys[i] >> 32) & 0xFFFF);
  atomicAdd(&hist[bin + ((blockIdx.x & 3) << 16)], 1);
}

// wide-grid replica merge (round-13 lesson: folding this into the single-block find
// quadruples its serial reads -> +30us/pool; keep the reduction wide)
__global__ void hist_merge_kernel(int* __restrict__ hist) {
  int b = blockIdx.x * 256 + threadIdx.x;   // 65536 bins
  hist[b] = hist[b] + hist[b + 65536] + hist[b + 2 * 65536] + hist[b + 3 * 65536];
}

// ---------- radix passes 2/3 histogram (prefix-filtered, low contention) ----------
__global__ void select_hist_kernel(const unsigned long long* __restrict__ keys, int N,
                                   const unsigned long long* __restrict__ prefix,
                                   int shift, unsigned long long M, int* __restrict__ hist) {
  int i = blockIdx.x * 256 + threadIdx.x;
  if (i >= N) return;
  unsigned long long P = *prefix;
  unsigned long long key = keys[i];
  if (((key ^ P) & M) == 0)
    atomicAdd(&hist[(int)((key >> shift) & 0xFFFF)], 1);
}

// find k-th digit; pass1 (shift==32) seeds prefix/rem from param k
__global__ void select_find_kernel(const int* __restrict__ hist,
                                   unsigned long long* __restrict__ prefix,
                                   int* __restrict__ rem, int shift, int* __restrict__ ctr,
                                   int k) {
  int t = threadIdx.x;            // 1024 threads
  int base = t * 64;
  int s = 0;
#pragma unroll
  for (int j = 0; j < 64; ++j) s += hist[base + j];
  int lane = t & 63, w = t >> 6;
  int v = s;
  for (int o = 1; o < 64; o <<= 1) { int u = __shfl_up(v, o, 64); if (lane >= o) v += u; }
  __shared__ int ws[16];
  if (lane == 63) ws[w] = v;
  __syncthreads();
  if (t < 16) {
    int u = ws[t];
    for (int o = 1; o < 16; o <<= 1) { int uu = __shfl_up(u, o, 64); if (t >= o) u += uu; }
    ws[t] = u;
  }
  __syncthreads();
  int incl = v + (w > 0 ? ws[w - 1] : 0);
  int excl = incl - s;
  int R = (shift == 32) ? k : *rem;
  if (excl < R && incl >= R) {
    int c = excl, b = base;
    for (int j = 0; j < 64; ++j) {
      int h = hist[base + j];
      if (c + h >= R) { b = base + j; break; }
      c += h;
    }
    if (shift == 32) *prefix = ((unsigned long long)b) << shift;
    else             *prefix |= ((unsigned long long)b) << shift;
    *rem = R - c;
    if (shift == 0) *ctr = 0;
  }
}

__global__ void select_enum_kernel(const unsigned long long* __restrict__ keys, int N,
                                   const unsigned long long* __restrict__ Tptr,
                                   int* __restrict__ ctr, int* __restrict__ perm,
                                   int* __restrict__ nm) {
  int i = blockIdx.x * 256 + threadIdx.x;
  if (i >= N) return;
  unsigned long long T = *Tptr;
  if (keys[i] <= T) { int r = atomicAdd(ctr, 1); perm[r] = i; nm[i] = r; }
  else nm[i] = -1;
}

// ---------- pooled features: xnew[j] = xold[perm[j]] * score[perm[j]] ----------
// (standalone: fusing this gather into the k-tiled GEMM re-gathers 4x — round-12 lesson)
__global__ void pool_gather_kernel(const float* __restrict__ xold, const float* __restrict__ score,
                                   const int* __restrict__ perm, float* __restrict__ xnew, int k) {
  int j = blockIdx.x * 2 + (threadIdx.x >> 7);
  int f = threadIdx.x & 127;
  if (j >= k) return;
  int src = perm[j];
  xnew[(size_t)j * C_HID + f] = xold[(size_t)src * C_HID + f] * score[src];
}

// ---------- edge relabel chain ----------
DEV bool map_edge(int a, int b, const int* m0, const int* m1, int& r, int& c) {
  r = a; c = b;
  if (m0) { r = m0[r]; c = m0[c]; if ((r | c) < 0) return false; }
  if (m1) { r = m1[r]; c = m1[c]; if ((r | c) < 0) return false; }
  return true;
}

// level 0: plain count (identity mapping)
__global__ void edge_count_kernel(const int* __restrict__ ei, int E, int* __restrict__ cnt) {
  int e = blockIdx.x * 256 + threadIdx.x;
  if (e >= E) return;
  atomicAdd(&cnt[ei[e]], 1);
}

__global__ void edge_fill_kernel(const int* __restrict__ ei, int E,
                                 const int* __restrict__ rowptr, int* __restrict__ fc,
                                 int* __restrict__ colv) {
  int e = blockIdx.x * 256 + threadIdx.x;
  if (e >= E) return;
  int r = ei[e], c = ei[E + e];
  int pos = rowptr[r] + atomicAdd(&fc[r], 1);
  colv[pos] = c;
}

// mapped levels: count + compact surviving (r,c) pairs; block-aggregated pctr atomic.
#define CEPT 7
__global__ __launch_bounds__(1024) void edge_count_compact_kernel(
    const int* __restrict__ ei, int E, const int* m0, const int* m1,
    int* __restrict__ cnt, int2* __restrict__ pairs, int* __restrict__ pctr) {
  int tid = threadIdx.x;
  int gbase = blockIdx.x * (1024 * CEPT) + tid;
  int rs[CEPT], cs[CEPT];
  int myn = 0;
#pragma unroll
  for (int i = 0; i < CEPT; ++i) {
    int e = gbase + i * 1024;
    int r, c;
    bool keep = (e < E) && map_edge(ei[e], ei[E + e], m0, m1, r, c);
    rs[i] = keep ? r : -1;
    cs[i] = keep ? c : 0;
    if (keep) { atomicAdd(&cnt[r], 1); ++myn; }
  }
  int lane = tid & 63, w = tid >> 6;
  int v = myn;
  for (int o = 1; o < 64; o <<= 1) { int u = __shfl_up(v, o, 64); if (lane >= o) v += u; }
  __shared__ int ws[16];
  __shared__ int bbase;
  if (lane == 63) ws[w] = v;
  __syncthreads();
  if (tid < 16) {
    int u = ws[tid];
    for (int o = 1; o < 16; o <<= 1) { int uu = __shfl_up(u, o, 64); if (tid >= o) u += uu; }
    ws[tid] = u;
  }
  __syncthreads();
  int excl = v - myn + (w > 0 ? ws[w - 1] : 0);
  if (tid == 1023) bbase = atomicAdd(pctr, excl + myn);
  __syncthreads();
  int pos = bbase + excl;
#pragma unroll
  for (int i = 0; i < CEPT; ++i)
    if (rs[i] >= 0) pairs[pos++] = make_int2(rs[i], cs[i]);
}

__global__ void edge_fill_compact_kernel(const int2* __restrict__ pairs, const int* __restrict__ pctr,
                                         const int* __restrict__ rowptr, int* __restrict__ fc,
                                         int* __restrict__ colv) {
  int i = blockIdx.x * 256 + threadIdx.x;
  if (i >= *pctr) return;
  int2 pr = pairs[i];
  int pos = rowptr[pr.x] + atomicAdd(&fc[pr.x], 1);
  colv[pos] = pr.y;
}

// ---------- wide 3-phase scan (+ fused dinv, fc=0) ----------
__global__ void scan_partial_kernel(const int* __restrict__ cnt, int n, int* __restrict__ bsum) {
  int i = blockIdx.x * 256 + threadIdx.x;
  int v = (i < n) ? cnt[i] : 0;
#pragma unroll
  for (int o = 32; o > 0; o >>= 1) v += __shfl_down(v, o, 64);
  __shared__ int ws[4];
  if ((threadIdx.x & 63) == 0) ws[threadIdx.x >> 6] = v;
  __syncthreads();
  if (threadIdx.x == 0) bsum[blockIdx.x] = ws[0] + ws[1] + ws[2] + ws[3];
}

__global__ void scan_blocksums_kernel(int* __restrict__ bsum, int nb) {
  int t = threadIdx.x;
  int v = (t < nb) ? bsum[t] : 0;
  int lane = t & 63, w = t >> 6;
  for (int o = 1; o < 64; o <<= 1) { int u = __shfl_up(v, o, 64); if (lane >= o) v += u; }
  __shared__ int ws[16];
  if (lane == 63) ws[w] = v;
  __syncthreads();
  if (t < 16) {
    int u = ws[t];
    for (int o = 1; o < 16; o <<= 1) { int uu = __shfl_up(u, o, 64); if (t >= o) u += uu; }
    ws[t] = u;
  }
  __syncthreads();
  if (t < nb) bsum[t] = v + (w > 0 ? ws[w - 1] : 0);
}

__global__ void scan_scatter_kernel(const int* __restrict__ cnt, int n,
                                    const int* __restrict__ bsum,
                                    int* __restrict__ rowptr, float* __restrict__ dinv,
                                    int* __restrict__ fc) {
  int i = blockIdx.x * 256 + threadIdx.x;
  int v = (i < n) ? cnt[i] : 0;
  int lane = threadIdx.x & 63, w = threadIdx.x >> 6;
  int s = v;
  for (int o = 1; o < 64; o <<= 1) { int u = __shfl_up(s, o, 64); if (lane >= o) s += u; }
  __shared__ int ws[4];
  __shared__ int wo[4];
  if (lane == 63) ws[w] = s;
  __syncthreads();
  if (threadIdx.x == 0) { int c = 0; for (int j = 0; j < 4; ++j) { wo[j] = c; c += ws[j]; } }
  __syncthreads();
  int excl = s - v + wo[w] + (blockIdx.x > 0 ? bsum[blockIdx.x - 1] : 0);
  if (i < n) {
    rowptr[i] = excl;
    dinv[i] = rsqrtf((float)v + 1.0f);
    fc[i] = 0;
    if (i == n - 1) rowptr[n] = excl + v;
  }
}

// ---------- fp32 SpMM hop (pre-pool convs) ----------
template <int FIRST, int RELU>
__global__ void spmm_kernel(const int* __restrict__ rowptr, const int* __restrict__ colv,
                            const float* __restrict__ dinv,
                            const float* __restrict__ h_in, const float* __restrict__ x0,
                            float* __restrict__ out, int M, int C) {
  int lanes = C >> 2;
  int rpb = 256 / lanes;
  int r = blockIdx.x * rpb + (int)threadIdx.x / lanes;
  int lane = (int)threadIdx.x % lanes;
  if (r >= M) return;
  float d = dinv[r];
  const float4* hin4 = (const float4*)h_in;
  size_t base = (size_t)r * lanes + lane;
  float4 self = hin4[base];
  float sn = d * d;
  float4 v = make_float4(sn * self.x, sn * self.y, sn * self.z, sn * self.w);
  int e0 = rowptr[r], e1 = rowptr[r + 1];
  int e = e0;
  for (; e + 8 <= e1; e += 8) {
    int cc[8];
#pragma unroll
    for (int i = 0; i < 8; ++i) cc[i] = colv[e + i];
    float4 hh[8];
#pragma unroll
    for (int i = 0; i < 8; ++i) hh[i] = hin4[(size_t)cc[i] * lanes + lane];
    float ww[8];
#pragma unroll
    for (int i = 0; i < 8; ++i) ww[i] = d * dinv[cc[i]];
#pragma unroll
    for (int i = 0; i < 8; ++i) v = f4_fma(ww[i], hh[i], v);
  }
  for (; e < e1; ++e) {
    int c = colv[e];
    float w = d * dinv[c];
    float4 h = hin4[(size_t)c * lanes + lane];
    v = f4_fma(w, h, v);
  }
  if (FIRST) {
    ((float4*)out)[base] = v;
  } else {
    float4 a = ((const float4*)x0)[base];
    a.x += self.x + v.x; a.y += self.y + v.y; a.z += self.z + v.z; a.w += self.w + v.w;
    if (RELU) { a.x = fmaxf(a.x, 0.f); a.y = fmaxf(a.y, 0.f); a.z = fmaxf(a.z, 0.f); a.w = fmaxf(a.w, 0.f); }
    ((float4*)out)[base] = a;
  }
}

// ---------- bf16-gather SpMM hop (POST-POOL ONLY) ----------
template <int FIRST, int RELU>
__global__ void spmm_bf16_kernel(const int* __restrict__ rowptr, const int* __restrict__ colv,
                                 const float* __restrict__ dinv,
                                 const ushort* __restrict__ hb, const float* __restrict__ x0,
                                 void* __restrict__ outp, int M, int C) {
  int lanes = C >> 2;
  int rpb = 256 / lanes;
  int r = blockIdx.x * rpb + (int)threadIdx.x / lanes;
  int lane = (int)threadIdx.x % lanes;
  if (r >= M) return;
  float d = dinv[r];
  const uint2* hb2 = (const uint2*)hb;
  size_t base = (size_t)r * lanes + lane;
  float4 self = bfunpack4(hb2[base]);
  float sn = d * d;
  float4 v = make_float4(sn * self.x, sn * self.y, sn * self.z, sn * self.w);
  int e0 = rowptr[r], e1 = rowptr[r + 1];
  int e = e0;
  for (; e + 8 <= e1; e += 8) {
    int cc[8];
#pragma unroll
    for (int i = 0; i < 8; ++i) cc[i] = colv[e + i];
    uint2 hh[8];
#pragma unroll
    for (int i = 0; i < 8; ++i) hh[i] = hb2[(size_t)cc[i] * lanes + lane];
    float ww[8];
#pragma unroll
    for (int i = 0; i < 8; ++i) ww[i] = d * dinv[cc[i]];
#pragma unroll
    for (int i = 0; i < 8; ++i) v = f4_fma(ww[i], bfunpack4(hh[i]), v);
  }
  for (; e < e1; ++e) {
    int c = colv[e];
    float w = d * dinv[c];
    v = f4_fma(w, bfunpack4(hb2[(size_t)c * lanes + lane]), v);
  }
  if (FIRST) {
    ((uint2*)outp)[base] = bfpack4(v);
  } else {
    float4 a = ((const float4*)x0)[base];
    a.x += self.x + v.x; a.y += self.y + v.y; a.z += self.z + v.z; a.w += self.w + v.w;
    if (RELU) { a.x = fmaxf(a.x, 0.f); a.y = fmaxf(a.y, 0.f); a.z = fmaxf(a.z, 0.f); a.w = fmaxf(a.w, 0.f); }
    ((float4*)outp)[base] = a;
  }
}

// ---------- GEMM: C[M,NC] = A1eff @ W (+addv); optional bf16 mirror of output ----------
template <int NC, int KT, int SKIP, int ADDIN, int MIRROR>
__global__ __launch_bounds__(256) void gemm_kernel(const float* __restrict__ A1, int K1,
                                                   const float* __restrict__ W,
                                                   float* __restrict__ Cd, int M,
                                                   const float* __restrict__ up,
                                                   const int* __restrict__ nm,
                                                   const float* __restrict__ addv,
                                                   ushort* __restrict__ bh) {
  constexpr int KTILE = 32;
  constexpr int AP = KTILE + 4;
  constexpr int CG = NC / 4;
  constexpr int RG = 256 / CG;
  constexpr int RPT = 64 / RG;
  __shared__ float Wl[KTILE * NC];
  __shared__ float Al[64 * AP];
  int tid = threadIdx.x;
  int r0 = blockIdx.x * 64;
  int cg = tid % CG, rg = tid / CG;
  float4 acc[RPT];
#pragma unroll
  for (int m = 0; m < RPT; ++m) acc[m] = make_float4(0.f, 0.f, 0.f, 0.f);

  for (int k0 = 0; k0 < KT; k0 += KTILE) {
    const float4* Wg = (const float4*)(W + (size_t)k0 * NC);
    for (int idx = tid; idx < KTILE * NC / 4; idx += 256)
      ((float4*)Wl)[idx] = Wg[idx];
#pragma unroll
    for (int s = 0; s < (64 * KTILE / 4) / 256; ++s) {
      int f4i = tid + s * 256;
      int row = f4i >> 3;
      int kk = (f4i & 7) << 2;
      int gr = r0 + row, gk = k0 + kk;
      float4 v = make_float4(0.f, 0.f, 0.f, 0.f);
      if (gr < M) {
        v = *(const float4*)(A1 + (size_t)gr * K1 + gk);
        if (SKIP) {
          int j = nm[gr];
          if (j >= 0) {
            float4 u = *(const float4*)(up + (size_t)j * K1 + gk);
            v.x += u.x; v.y += u.y; v.z += u.z; v.w += u.w;
          }
        }
      }
      *(float4*)&Al[row * AP + kk] = v;
    }
    __syncthreads();
#pragma unroll
    for (int kk0 = 0; kk0 < KTILE; kk0 += 4) {
      float4 a4[RPT];
#pragma unroll
      for (int m = 0; m < RPT; ++m)
        a4[m] = *(const float4*)&Al[(rg * RPT + m) * AP + kk0];
#pragma unroll
      for (int j = 0; j < 4; ++j) {
        float4 w = *(const float4*)&Wl[(kk0 + j) * NC + cg * 4];
#pragma unroll
        for (int m = 0; m < RPT; ++m) {
          float a = (j == 0) ? a4[m].x : (j == 1) ? a4[m].y : (j == 2) ? a4[m].z : a4[m].w;
          acc[m] = f4_fma(a, w, acc[m]);
        }
      }
    }
    __syncthreads();
  }
#pragma unroll
  for (int m = 0; m < RPT; ++m) {
    int gr = r0 + rg * RPT + m;
    if (gr < M) {
      float4 o = acc[m];
      if (ADDIN) {
        float4 u = *(const float4*)(addv + (size_t)gr * NC + cg * 4);
        o.x += u.x; o.y += u.y; o.z += u.z; o.w += u.w;
      }
      *(float4*)(Cd + (size_t)gr * NC + cg * 4) = o;
      if (MIRROR) ((uint2*)bh)[(size_t)gr * CG + cg] = bfpack4(o);
    }
  }
}

extern "C" void kernel_launch(void* const* d_in, const int* in_sizes, int n_in,
                              void* d_out, int out_size, void* d_ws, size_t ws_size,
                              hipStream_t stream) {
  const float* x   = (const float*)d_in[0];
  const int*   ei  = (const int*)d_in[1];
  const float* Wd0 = (const float*)d_in[2];
  const float* Wd1 = (const float*)d_in[3];
  const float* Wd2 = (const float*)d_in[4];
  const float* pw0 = (const float*)d_in[5];
  const float* pw1 = (const float*)d_in[6];
  const float* Wu0 = (const float*)d_in[7];
  const float* Wu1 = (const float*)d_in[8];
  const float* Wu2 = (const float*)d_in[9];
  float* out = (float*)d_out;

  const int C = C_HID;
  int N0 = in_sizes[0] / C;       // 50000 (idx fits 16 bits -> 48-bit select keys)
  int E  = in_sizes[1] / 2;       // 800000
  int k1 = (N0 + 1) / 2;
  int k2 = (k1 + 1) / 2;

  char* p = (char*)d_ws;
  auto alloc = [&](size_t bytes) { char* q = p; p += (bytes + 255) & ~(size_t)255; return q; };
  float* org   = (float*)alloc((size_t)N0 * C * 4);
  float* b0    = (float*)alloc((size_t)N0 * C * 4);
  float* b1    = (float*)alloc((size_t)N0 * C * 4);
  float* b2    = (float*)alloc((size_t)N0 * C * 4);
  float* x1res = (float*)alloc((size_t)k1 * C * 4);
  ushort* bh   = (ushort*)alloc((size_t)N0 * C * 2);
  ushort* h1h  = (ushort*)alloc((size_t)N0 * C * 2);
  float* score = (float*)alloc((size_t)N0 * 4);
  unsigned long long* keys = (unsigned long long*)alloc((size_t)N0 * 8);
  int* perm0 = (int*)alloc((size_t)k1 * 4);
  int* perm1 = (int*)alloc((size_t)k2 * 4);
  int* map0  = (int*)alloc((size_t)N0 * 4);
  int* map1  = (int*)alloc((size_t)k1 * 4);
  int* cnt   = (int*)alloc((size_t)N0 * 4);
  int* fc    = (int*)alloc((size_t)N0 * 4);
  int* rp0   = (int*)alloc((size_t)(N0 + 1) * 4);
  int* rp1   = (int*)alloc((size_t)(k1 + 1) * 4);
  int* rp2   = (int*)alloc((size_t)(k2 + 1) * 4);
  float* dinv0 = (float*)alloc((size_t)N0 * 4);
  float* dinv1 = (float*)alloc((size_t)k1 * 4);
  float* dinv2 = (float*)alloc((size_t)k2 * 4);
  int* col0 = (int*)alloc((size_t)E * 4);
  int* col1 = (int*)alloc((size_t)E * 4);
  int* col2 = (int*)alloc((size_t)E * 4);
  int2* pairs = (int2*)alloc((size_t)E * 8);
  // per pool: 4 pass-1 replicas + pass2 + pass3 = 6 slices of 65536
  int* hist12 = (int*)alloc((size_t)12 * 65536 * 4);
  int* bsum = (int*)alloc(1024 * 4);
  float* Wcat1 = (float*)alloc((size_t)128 * 64 * 4);
  unsigned long long* selT = (unsigned long long*)alloc(64);
  int* selRem = (int*)alloc(64);
  int* selCtr = (int*)alloc(64);
  int* pctr = (int*)alloc(64);

  dim3 b256(256);
  int egrid = (E + 255) / 256;
  int cgrid = (E + 1024 * CEPT - 1) / (1024 * CEPT);
  int g0_128 = (N0 + 7) / 8;
  int g1_128 = (k1 + 7) / 8;
  int g2_128 = (k2 + 7) / 8;
  int g0_64  = (N0 + 15) / 16;

  auto scan_csr = [&](int n, int* rowptr, float* dinv) {
    int g = (n + 255) / 256;
    scan_partial_kernel<<<g, b256, 0, stream>>>(cnt, n, bsum);
    scan_blocksums_kernel<<<1, 1024, 0, stream>>>(bsum, g);
    scan_scatter_kernel<<<g, b256, 0, stream>>>(cnt, n, bsum, rowptr, dinv, fc);
  };

  auto topk_select = [&](int N, int k, int* perm, int* nm, int* histb) {
    int g = (N + 255) / 256;
    select_hist1_kernel<<<g, b256, 0, stream>>>(keys, N, histb);
    hist_merge_kernel<<<256, b256, 0, stream>>>(histb);
    select_find_kernel<<<1, 1024, 0, stream>>>(histb, selT, selRem, 32, selCtr, k);
    select_hist_kernel<<<g, b256, 0, stream>>>(keys, N, selT, 16, ~0ull << 32, histb + 4 * 65536);
    select_find_kernel<<<1, 1024, 0, stream>>>(histb + 4 * 65536, selT, selRem, 16, selCtr, k);
    select_hist_kernel<<<g, b256, 0, stream>>>(keys, N, selT, 0, ~0ull << 16, histb + 5 * 65536);
    select_find_kernel<<<1, 1024, 0, stream>>>(histb + 5 * 65536, selT, selRem, 0, selCtr, k);
    select_enum_kernel<<<g, b256, 0, stream>>>(keys, N, selT, selCtr, perm, nm);
  };

  // zero all radix histograms once per call
  hipMemsetAsync(hist12, 0, (size_t)12 * 65536 * 4, stream);

  // ======== Wcat1 prep: Wcat1 = Wu1 @ Wu2[0:128]  [128x64]
  gemm_kernel<64, 128, 0, 0, 0><<<2, b256, 0, stream>>>(Wu1, 128, Wu2, Wcat1, 128, nullptr, nullptr, nullptr, nullptr);

  // ======== CSR level 0 ========
  hipMemsetAsync(cnt, 0, (size_t)N0 * 4, stream);
  edge_count_kernel<<<egrid, b256, 0, stream>>>(ei, E, cnt);
  scan_csr(N0, rp0, dinv0);
  edge_fill_kernel<<<egrid, b256, 0, stream>>>(ei, E, rp0, fc, col0);

  // ======== conv0 (PRE-POOL -> fp32): org = relu(x' + h1 + h2), x' = x @ Wd0 ========
  gemm_kernel<128, 128, 0, 0, 0><<<(N0 + 63) / 64, b256, 0, stream>>>(x, 128, Wd0, b0, N0, nullptr, nullptr, nullptr, nullptr);
  spmm_kernel<1, 0><<<g0_128, b256, 0, stream>>>(rp0, col0, dinv0, b0, nullptr, b1, N0, 128);
  spmm_kernel<0, 1><<<g0_128, b256, 0, stream>>>(rp0, col0, dinv0, b1, b0, org, N0, 128);

  // ======== pool0 ========
  scorekeys_kernel<<<(N0 + 3) / 4, b256, 0, stream>>>(org, pw0, score, keys, N0);
  topk_select(N0, k1, perm0, map0, hist12);
  pool_gather_kernel<<<(k1 + 1) / 2, b256, 0, stream>>>(org, score, perm0, b0, k1);

  // ======== CSR level 1 ========
  hipMemsetAsync(cnt, 0, (size_t)k1 * 4, stream);
  hipMemsetAsync(pctr, 0, 4, stream);
  edge_count_compact_kernel<<<cgrid, 1024, 0, stream>>>(ei, E, map0, nullptr, cnt, pairs, pctr);
  scan_csr(k1, rp1, dinv1);
  edge_fill_compact_kernel<<<egrid, b256, 0, stream>>>(pairs, pctr, rp1, fc, col1);

  // ======== conv1 (PRE-POOL -> fp32): x1res = relu(prop(b0 @ Wd1)) ========
  gemm_kernel<128, 128, 0, 0, 0><<<(k1 + 63) / 64, b256, 0, stream>>>(b0, 128, Wd1, b1, k1, nullptr, nullptr, nullptr, nullptr);
  spmm_kernel<1, 0><<<g1_128, b256, 0, stream>>>(rp1, col1, dinv1, b1, nullptr, b2, k1, 128);
  spmm_kernel<0, 1><<<g1_128, b256, 0, stream>>>(rp1, col1, dinv1, b2, b1, x1res, k1, 128);

  // ======== pool1 ========
  scorekeys_kernel<<<(k1 + 3) / 4, b256, 0, stream>>>(x1res, pw1, score, keys, k1);
  topk_select(k1, k2, perm1, map1, hist12 + 6 * 65536);
  pool_gather_kernel<<<(k2 + 1) / 2, b256, 0, stream>>>(x1res, score, perm1, b0, k2);

  // ======== CSR level 2 ========
  hipMemsetAsync(cnt, 0, (size_t)k2 * 4, stream);
  hipMemsetAsync(pctr, 0, 4, stream);
  edge_count_compact_kernel<<<cgrid, 1024, 0, stream>>>(ei, E, map0, map1, cnt, pairs, pctr);
  scan_csr(k2, rp2, dinv2);
  edge_fill_compact_kernel<<<egrid, b256, 0, stream>>>(pairs, pctr, rp2, fc, col2);

  // ======== conv2 (post-pool -> bf16 gathers): b0 = relu(prop(b0 @ Wd2)) ========
  gemm_kernel<128, 128, 0, 0, 1><<<(k2 + 63) / 64, b256, 0, stream>>>(b0, 128, Wd2, b1, k2, nullptr, nullptr, nullptr, bh);
  spmm_bf16_kernel<1, 0><<<g2_128, b256, 0, stream>>>(rp2, col2, dinv2, bh, nullptr, h1h, k2, 128);
  spmm_bf16_kernel<0, 1><<<g2_128, b256, 0, stream>>>(rp2, col2, dinv2, h1h, b1, b0, k2, 128);

  // ======== up0 (post-pool -> bf16): b0 = relu(prop((x1res + up(b0)) @ Wu0)) ========
  gemm_kernel<128, 128, 1, 0, 1><<<(k1 + 63) / 64, b256, 0, stream>>>(x1res, 128, Wu0, b1, k1, b0, map1, nullptr, bh);
  spmm_bf16_kernel<1, 0><<<g1_128, b256, 0, stream>>>(rp1, col1, dinv1, bh, nullptr, h1h, k1, 128);
  spmm_bf16_kernel<0, 1><<<g1_128, b256, 0, stream>>>(rp1, col1, dinv1, h1h, b1, b0, k1, 128);

  // ======== up1+final fusion (post-pool -> bf16 gathers, fp32 accumulate):
  //   out = P( P((org+up)@Wcat1) + org @ Wu2b ),  Wcat1 = Wu1@Wu2a
  gemm_kernel<64, 128, 1, 0, 1><<<(N0 + 63) / 64, b256, 0, stream>>>(org, 128, Wcat1, b2, N0, b0, map0, nullptr, bh);
  spmm_bf16_kernel<1, 0><<<g0_64, b256, 0, stream>>>(rp0, col0, dinv0, bh, nullptr, h1h, N0, 64);
  spmm_bf16_kernel<0, 0><<<g0_64, b256, 0, stream>>>(rp0, col0, dinv0, h1h, b2, b2, N0, 64);
  gemm_kernel<64, 128, 0, 1, 1><<<(N0 + 63) / 64, b256, 0, stream>>>(org, 128, Wu2 + (size_t)128 * 64, b0, N0, nullptr, nullptr, b2, bh);
  spmm_bf16_kernel<1, 0><<<g0_64, b256, 0, stream>>>(rp0, col0, dinv0, bh, nullptr, h1h, N0, 64);
  spmm_bf16_kernel<0, 0><<<g0_64, b256, 0, stream>>>(rp0, col0, dinv0, h1h, b0, out, N0, 64);
}